// Round 1
// baseline (3567.764 us; speedup 1.0000x reference)
//
#include <hip/hip_runtime.h>

#define NWG 16   // workgroups per direction in the recurrence

__device__ __forceinline__ float sigf(float x){ return 1.0f/(1.0f + __expf(-x)); }
// tanh(x) = 1 - 2/(e^{2x}+1); saturates cleanly to +-1 without NaN at extremes
__device__ __forceinline__ float tanhf_fast(float x){ float e = __expf(2.0f*x); return 1.0f - 2.0f/(e+1.0f); }
// swizzled word index for h storage: float4 {h[b=0..3][k]} at words hswz(k)..+3
// bank(k) = (8k + 4*((k>>4)&7)) % 32 -> 2-way max conflict for the dot-loop read pattern
__device__ __forceinline__ int hswz(int k){ return (k<<3) + (((k>>4)&7)<<2); }

// ---------------- embedding gather: x[m][e] = emb[ids[m]][e], m = b*256+t ----------------
__global__ void k_embed(const int* __restrict__ ids, const float* __restrict__ emb, float* __restrict__ x){
  int i = blockIdx.x*256 + threadIdx.x;          // < 1024*128
  x[i] = emb[(ids[i>>7]<<7) + (i&127)];
}

// ---------------- generic fp32 GEMM: C[M][N] = A[M][K] @ W[N][K]^T (+bias[n]) ----------------
// tiles 64x64, 256 threads, 4x4 microtile, K%16==0, M from gridDim.x*64, N from gridDim.y*64
__global__ __launch_bounds__(256) void k_gemm_bias(
    const float* __restrict__ A, const float* __restrict__ W, const float* __restrict__ bias,
    float* __restrict__ C, int N, int K){
  __shared__ float As[16][68];   // [k][m] transposed stage
  __shared__ float Ws[16][68];   // [k][n]
  int tid = threadIdx.x;
  int tr = tid>>4, tc = tid&15;
  int m0 = blockIdx.x<<6, n0 = blockIdx.y<<6;
  int rr = tid>>2, kq = (tid&3)<<2;
  const float* Ap = A + (size_t)(m0+rr)*K + kq;
  const float* Wp = W + (size_t)(n0+rr)*K + kq;
  float acc[4][4] = {};
  for (int k0 = 0; k0 < K; k0 += 16){
    float4 av = *(const float4*)(Ap + k0);
    float4 wv = *(const float4*)(Wp + k0);
    __syncthreads();
    As[kq+0][rr]=av.x; As[kq+1][rr]=av.y; As[kq+2][rr]=av.z; As[kq+3][rr]=av.w;
    Ws[kq+0][rr]=wv.x; Ws[kq+1][rr]=wv.y; Ws[kq+2][rr]=wv.z; Ws[kq+3][rr]=wv.w;
    __syncthreads();
    #pragma unroll
    for (int kk=0;kk<16;kk++){
      float4 a = *(const float4*)&As[kk][tr<<2];
      float4 b = *(const float4*)&Ws[kk][tc<<2];
      acc[0][0]=fmaf(a.x,b.x,acc[0][0]); acc[0][1]=fmaf(a.x,b.y,acc[0][1]);
      acc[0][2]=fmaf(a.x,b.z,acc[0][2]); acc[0][3]=fmaf(a.x,b.w,acc[0][3]);
      acc[1][0]=fmaf(a.y,b.x,acc[1][0]); acc[1][1]=fmaf(a.y,b.y,acc[1][1]);
      acc[1][2]=fmaf(a.y,b.z,acc[1][2]); acc[1][3]=fmaf(a.y,b.w,acc[1][3]);
      acc[2][0]=fmaf(a.z,b.x,acc[2][0]); acc[2][1]=fmaf(a.z,b.y,acc[2][1]);
      acc[2][2]=fmaf(a.z,b.z,acc[2][2]); acc[2][3]=fmaf(a.z,b.w,acc[2][3]);
      acc[3][0]=fmaf(a.w,b.x,acc[3][0]); acc[3][1]=fmaf(a.w,b.y,acc[3][1]);
      acc[3][2]=fmaf(a.w,b.z,acc[3][2]); acc[3][3]=fmaf(a.w,b.w,acc[3][3]);
    }
  }
  #pragma unroll
  for (int i=0;i<4;i++){
    int m = m0 + (tr<<2) + i;
    #pragma unroll
    for (int j=0;j<4;j++){
      int n = n0 + (tc<<2) + j;
      float v = acc[i][j];
      if (bias) v += bias[n];
      C[(size_t)m*N + n] = v;
    }
  }
}

// ---------------- persistent bidirectional LSTM layer ----------------
// grid = 32 (dir = bid/16, slice w = bid%16 owns hidden j in [16w,16w+16))
// 1024 threads: kc = tid&15 (k-chunk of 16), r = tid>>4 (64 gate rows: q = r>>4 gate, jj = r&15)
// W_hh slice in registers (16 floats/thread). h exchanged via global double buffer +
// device-scope atomic counter barrier (monotonic; release/acquire; placement-independent).
__global__ __launch_bounds__(1024) void k_lstm(
    const float* __restrict__ gx,    // [1024 m][2048]  n = dir*1024 + q*256 + j
    const float* __restrict__ whh,   // [2][1024][256]
    float* __restrict__ hcat,        // [1024 m][512]   out: dir*256 + j
    float* __restrict__ hbuf,        // [2 par][2 dir][4 b][256 j]
    unsigned* __restrict__ ctr){     // [2] per dir, starts at 0
  int bid = blockIdx.x;
  int dir = bid >> 4;
  int w   = bid & 15;
  int j0  = w << 4;
  int tid = threadIdx.x;
  int kc  = tid & 15;
  int r   = tid >> 4;
  int q   = r >> 4, jj = r & 15;
  int grow = (q<<8) + j0 + jj;       // gate row in [0,1024)

  float wreg[16];
  {
    const float* wp = whh + (size_t)(dir*1024 + grow)*256 + (kc<<4);
    #pragma unroll
    for (int i=0;i<16;i+=4){
      float4 v = *(const float4*)(wp + i);
      wreg[i]=v.x; wreg[i+1]=v.y; wreg[i+2]=v.z; wreg[i+3]=v.w;
    }
  }

  __shared__ float h_swz[256*8 + 32];   // swizzled [k]{b0..b3}
  __shared__ float c_lds[4][16];
  __shared__ float gate_lds[4][64];
  for (int i = tid; i < 256*8+32; i += 1024) h_swz[i] = 0.0f;
  if (tid < 64) c_lds[tid>>4][tid&15] = 0.0f;
  __syncthreads();

  unsigned* mycnt = ctr + dir;
  const int hb_base = dir*1024;   // + par*2048

  for (int s = 0; s < 256; s++){
    int t = dir ? (255 - s) : s;
    // prefetch gx for the nonlinearity threads (issued early, hidden under dot)
    float gxv0=0, gxv1=0, gxv2=0, gxv3=0;
    if (tid < 64){
      int b = tid>>4, j2 = tid&15;
      const float* gp = gx + (size_t)((b<<8) + t)*2048 + dir*1024 + j0 + j2;
      gxv0 = gp[0]; gxv1 = gp[256]; gxv2 = gp[512]; gxv3 = gp[768];
    }
    // gate dot: acc[b] = sum_k W_hh[grow][k] * h[b][k] over k in [16kc,16kc+16)
    float a0=0.f,a1=0.f,a2=0.f,a3=0.f;
    {
      int base = (kc<<7) + ((kc&7)<<2);   // hswz(kc*16)
      #pragma unroll
      for (int kk=0; kk<16; kk++){
        float4 hb = *(const float4*)&h_swz[base + (kk<<3)];
        a0 = fmaf(wreg[kk], hb.x, a0);
        a1 = fmaf(wreg[kk], hb.y, a1);
        a2 = fmaf(wreg[kk], hb.z, a2);
        a3 = fmaf(wreg[kk], hb.w, a3);
      }
    }
    #pragma unroll
    for (int m=1; m<16; m<<=1){
      a0 += __shfl_xor(a0, m, 64);
      a1 += __shfl_xor(a1, m, 64);
      a2 += __shfl_xor(a2, m, 64);
      a3 += __shfl_xor(a3, m, 64);
    }
    if (kc == 0){
      gate_lds[0][r]=a0; gate_lds[1][r]=a1; gate_lds[2][r]=a2; gate_lds[3][r]=a3;
    }
    __syncthreads();
    if (tid < 64){
      int b = tid>>4, j2 = tid&15;
      float gi = gxv0 + gate_lds[b][ 0+j2];
      float gf = gxv1 + gate_lds[b][16+j2];
      float gg = gxv2 + gate_lds[b][32+j2];
      float go = gxv3 + gate_lds[b][48+j2];
      float c  = sigf(gf)*c_lds[b][j2] + sigf(gi)*tanhf_fast(gg);
      c_lds[b][j2] = c;
      float h  = sigf(go)*tanhf_fast(c);
      __hip_atomic_store(&hbuf[((s&1)<<11) + hb_base + (b<<8) + j0 + j2], h,
                         __ATOMIC_RELAXED, __HIP_MEMORY_SCOPE_AGENT);
      hcat[(size_t)((b<<8) + t)*512 + (dir<<8) + j0 + j2] = h;
    }
    __syncthreads();   // all stores issued before signal
    if (tid == 0){
      __hip_atomic_fetch_add(mycnt, 1u, __ATOMIC_RELEASE, __HIP_MEMORY_SCOPE_AGENT);
      unsigned target = (unsigned)(NWG*(s+1));
      while (__hip_atomic_load(mycnt, __ATOMIC_ACQUIRE, __HIP_MEMORY_SCOPE_AGENT) < target){
        __builtin_amdgcn_s_sleep(1);
      }
    }
    __syncthreads();
    // refill h for next step from the buffer just completed (par = s&1)
    {
      int k = tid & 255, bb = tid >> 8;
      float hv = __hip_atomic_load(&hbuf[((s&1)<<11) + hb_base + (bb<<8) + k],
                                   __ATOMIC_RELAXED, __HIP_MEMORY_SCOPE_AGENT);
      h_swz[hswz(k) + bb] = hv;
    }
    __syncthreads();
  }
}

// ---------------- fused additive attention + softmax + ctx + classifier ----------------
// one WG (256 thr) per (b,t); thread s computes score[b,t,s]; then softmax, ctx, logits
__global__ __launch_bounds__(256) void k_attn(
    const float* __restrict__ q, const float* __restrict__ kmat,
    const float* __restrict__ h, const float* __restrict__ v,
    const float* __restrict__ clsW, const float* __restrict__ clsb,
    float* __restrict__ out){
  int bt = blockIdx.x;           // b*256 + t
  int b  = bt >> 8;
  int tid = threadIdx.x;
  __shared__ float q_s[512], v_s[512], p_s[256], red[8], ctx_s[512], part[240];
  *(float2*)&q_s[tid<<1] = *(const float2*)&q[(size_t)bt*512 + (tid<<1)];
  *(float2*)&v_s[tid<<1] = *(const float2*)&v[tid<<1];
  __syncthreads();
  const float* kp = kmat + (size_t)((b<<8) + tid)*512;
  float sc = 0.f;
  for (int d=0; d<512; d+=4){
    float4 kv = *(const float4*)&kp[d];
    sc += v_s[d+0]*tanhf_fast(q_s[d+0]+kv.x)
        + v_s[d+1]*tanhf_fast(q_s[d+1]+kv.y)
        + v_s[d+2]*tanhf_fast(q_s[d+2]+kv.z)
        + v_s[d+3]*tanhf_fast(q_s[d+3]+kv.w);
  }
  int wv = tid>>6, lane = tid&63;
  float m = sc;
  #pragma unroll
  for (int o=1;o<64;o<<=1) m = fmaxf(m, __shfl_xor(m,o,64));
  if (lane==0) red[wv] = m;
  __syncthreads();
  m = fmaxf(fmaxf(red[0],red[1]), fmaxf(red[2],red[3]));
  float p = __expf(sc - m);
  p_s[tid] = p;
  float sum = p;
  #pragma unroll
  for (int o=1;o<64;o<<=1) sum += __shfl_xor(sum,o,64);
  if (lane==0) red[4+wv] = sum;
  __syncthreads();
  float inv = 1.0f/(red[4]+red[5]+red[6]+red[7]);
  // ctx for dims 2*tid, 2*tid+1
  float cx=0.f, cy=0.f;
  for (int s2=0; s2<256; s2++){
    float pw = p_s[s2];
    float2 hv = *(const float2*)&h[(size_t)((b<<8)+s2)*512 + (tid<<1)];
    cx = fmaf(pw, hv.x, cx); cy = fmaf(pw, hv.y, cy);
  }
  ctx_s[tid<<1] = cx*inv; ctx_s[(tid<<1)+1] = cy*inv;
  __syncthreads();
  if (tid < 240){
    int c = tid>>4, ch = tid&15;
    const float* wrow = clsW + (size_t)c*512 + (ch<<5);
    const float* cc = &ctx_s[ch<<5];
    float acc = 0.f;
    #pragma unroll
    for (int i=0;i<32;i++) acc = fmaf(wrow[i], cc[i], acc);
    part[tid] = acc;
  }
  __syncthreads();
  if (tid < 15){
    float o = clsb[tid];
    #pragma unroll
    for (int i=0;i<16;i++) o += part[(tid<<4)+i];
    out[(size_t)bt*15 + tid] = o;
  }
}

extern "C" void kernel_launch(void* const* d_in, const int* in_sizes, int n_in,
                              void* d_out, int out_size, void* d_ws, size_t ws_size,
                              hipStream_t stream){
  (void)in_sizes; (void)n_in; (void)out_size; (void)ws_size;
  const int*   ids    = (const int*)  d_in[0];
  const float* emb    = (const float*)d_in[1];
  const float* w_ih0  = (const float*)d_in[2];
  const float* w_hh0  = (const float*)d_in[3];
  const float* b0     = (const float*)d_in[4];
  const float* w_ih   = (const float*)d_in[5];
  const float* w_hh   = (const float*)d_in[6];
  const float* b      = (const float*)d_in[7];
  const float* attn_W = (const float*)d_in[8];
  const float* attn_U = (const float*)d_in[9];
  const float* attn_v = (const float*)d_in[10];
  const float* cls_W  = (const float*)d_in[11];
  const float* cls_b  = (const float*)d_in[12];
  float* out = (float*)d_out;

  float* ws   = (float*)d_ws;
  float* x    = ws;                  // 131072
  float* gx   = x  + 131072;         // 2097152 (1024 x 2048)
  float* hA   = gx + 2097152;        // 524288  (1024 x 512)
  float* hB   = hA + 524288;         // 524288
  float* hbuf = hB + 524288;         // 4096
  unsigned* ctr = (unsigned*)(hbuf + 4096);  // 16 uints
  float* qb   = gx;                  // reuse gx after recurrences done
  float* kb   = gx + 524288;

  hipMemsetAsync(ctr, 0, 64, stream);
  k_embed<<<512, 256, 0, stream>>>(ids, emb, x);

  dim3 gBig(16, 32);   // M=1024, N=2048
  dim3 gQK(16, 8);     // M=1024, N=512

  // layer 0
  k_gemm_bias<<<gBig, 256, 0, stream>>>(x, w_ih0, b0, gx, 2048, 128);
  k_lstm<<<32, 1024, 0, stream>>>(gx, w_hh0, hA, hbuf, ctr + 0);
  // layer 1
  k_gemm_bias<<<gBig, 256, 0, stream>>>(hA, w_ih, b, gx, 2048, 512);
  k_lstm<<<32, 1024, 0, stream>>>(gx, w_hh, hB, hbuf, ctr + 2);
  // layer 2
  k_gemm_bias<<<gBig, 256, 0, stream>>>(hB, w_ih + 2048*512, b + 2048, gx, 2048, 512);
  k_lstm<<<32, 1024, 0, stream>>>(gx, w_hh + 2048*256, hA, hbuf, ctr + 4);
  // attention projections
  k_gemm_bias<<<gQK, 256, 0, stream>>>(hA, attn_W, nullptr, qb, 512, 512);
  k_gemm_bias<<<gQK, 256, 0, stream>>>(hA, attn_U, nullptr, kb, 512, 512);
  // fused scores/softmax/ctx/classifier
  k_attn<<<1024, 256, 0, stream>>>(qb, kb, hA, attn_v, cls_W, cls_b, out);
}

// Round 2
// 3342.495 us; speedup vs baseline: 1.0674x; 1.0674x over previous
//
#include <hip/hip_runtime.h>

#define NWG 16   // workgroups per direction in the recurrence

__device__ __forceinline__ float sigf(float x){ return 1.0f/(1.0f + __expf(-x)); }
// tanh(x) = 1 - 2/(e^{2x}+1); saturates cleanly to +-1 without NaN at extremes
__device__ __forceinline__ float tanhf_fast(float x){ float e = __expf(2.0f*x); return 1.0f - 2.0f/(e+1.0f); }
// swizzled word index for h storage: float4 {h[b=0..3][k]} at words hswz(k)..+3
__device__ __forceinline__ int hswz(int k){ return (k<<3) + (((k>>4)&7)<<2); }

// ---------------- embedding gather ----------------
__global__ void k_embed(const int* __restrict__ ids, const float* __restrict__ emb, float* __restrict__ x){
  int i = blockIdx.x*256 + threadIdx.x;          // < 1024*128
  x[i] = emb[(ids[i>>7]<<7) + (i&127)];
}

// ---------------- generic fp32 GEMM: C[M][N] = A[M][K] @ W[N][K]^T (+bias[n]) ----------------
__global__ __launch_bounds__(256) void k_gemm_bias(
    const float* __restrict__ A, const float* __restrict__ W, const float* __restrict__ bias,
    float* __restrict__ C, int N, int K){
  __shared__ float As[16][68];   // [k][m] transposed stage
  __shared__ float Ws[16][68];   // [k][n]
  int tid = threadIdx.x;
  int tr = tid>>4, tc = tid&15;
  int m0 = blockIdx.x<<6, n0 = blockIdx.y<<6;
  int rr = tid>>2, kq = (tid&3)<<2;
  const float* Ap = A + (size_t)(m0+rr)*K + kq;
  const float* Wp = W + (size_t)(n0+rr)*K + kq;
  float acc[4][4] = {};
  for (int k0 = 0; k0 < K; k0 += 16){
    float4 av = *(const float4*)(Ap + k0);
    float4 wv = *(const float4*)(Wp + k0);
    __syncthreads();
    As[kq+0][rr]=av.x; As[kq+1][rr]=av.y; As[kq+2][rr]=av.z; As[kq+3][rr]=av.w;
    Ws[kq+0][rr]=wv.x; Ws[kq+1][rr]=wv.y; Ws[kq+2][rr]=wv.z; Ws[kq+3][rr]=wv.w;
    __syncthreads();
    #pragma unroll
    for (int kk=0;kk<16;kk++){
      float4 a = *(const float4*)&As[kk][tr<<2];
      float4 b = *(const float4*)&Ws[kk][tc<<2];
      acc[0][0]=fmaf(a.x,b.x,acc[0][0]); acc[0][1]=fmaf(a.x,b.y,acc[0][1]);
      acc[0][2]=fmaf(a.x,b.z,acc[0][2]); acc[0][3]=fmaf(a.x,b.w,acc[0][3]);
      acc[1][0]=fmaf(a.y,b.x,acc[1][0]); acc[1][1]=fmaf(a.y,b.y,acc[1][1]);
      acc[1][2]=fmaf(a.y,b.z,acc[1][2]); acc[1][3]=fmaf(a.y,b.w,acc[1][3]);
      acc[2][0]=fmaf(a.z,b.x,acc[2][0]); acc[2][1]=fmaf(a.z,b.y,acc[2][1]);
      acc[2][2]=fmaf(a.z,b.z,acc[2][2]); acc[2][3]=fmaf(a.z,b.w,acc[2][3]);
      acc[3][0]=fmaf(a.w,b.x,acc[3][0]); acc[3][1]=fmaf(a.w,b.y,acc[3][1]);
      acc[3][2]=fmaf(a.w,b.z,acc[3][2]); acc[3][3]=fmaf(a.w,b.w,acc[3][3]);
    }
  }
  #pragma unroll
  for (int i=0;i<4;i++){
    int m = m0 + (tr<<2) + i;
    #pragma unroll
    for (int j=0;j<4;j++){
      int n = n0 + (tc<<2) + j;
      float v = acc[i][j];
      if (bias) v += bias[n];
      C[(size_t)m*N + n] = v;
    }
  }
}

// ---------------- persistent bidirectional LSTM layer ----------------
// grid = 32 (dir = bid/16, slice w = bid%16 owns hidden j in [16w,16w+16))
// Barrier: per-WG epoch flags (128B apart, NO atomic RMW). Producer wave release-stores
// its flag after its 64 h-stores (wave-wide vmcnt covers them); 16 lanes poll the 16
// flags of the direction in parallel -> one latency round trip, no RMW convoy.
__global__ __launch_bounds__(1024) void k_lstm(
    const float* __restrict__ gx,    // [1024 m][2048]  n = dir*1024 + q*256 + j
    const float* __restrict__ whh,   // [2][1024][256]
    float* __restrict__ hcat,        // [1024 m][512]   out: dir*256 + j
    float* __restrict__ hbuf,        // [2 dir][2 par][4 b][256 j]
    unsigned* __restrict__ flags){   // [2 dir][16 slot * 32 words], zeroed
  int bid = blockIdx.x;
  int dir = bid >> 4;
  int w   = bid & 15;
  int j0  = w << 4;
  int tid = threadIdx.x;
  int kc  = tid & 15;
  int r   = tid >> 4;
  int grow = ((r>>4)<<8) + j0 + (r&15);   // gate row in [0,1024)

  float wreg[16];
  {
    const float* wp = whh + (size_t)(dir*1024 + grow)*256 + (kc<<4);
    #pragma unroll
    for (int i=0;i<16;i+=4){
      float4 v = *(const float4*)(wp + i);
      wreg[i]=v.x; wreg[i+1]=v.y; wreg[i+2]=v.z; wreg[i+3]=v.w;
    }
  }

  __shared__ float h_swz[256*8 + 32];   // swizzled [k]{b0..b3}
  __shared__ float gate_lds[4][64];
  for (int i = tid; i < 256*8+32; i += 1024) h_swz[i] = 0.0f;
  __syncthreads();

  unsigned* myflags = flags + dir*512;      // 16 slots * 32 words (128B spacing)
  float* hb = hbuf + dir*2048;
  float c_reg = 0.0f;                       // cell state lives in wave 0 registers

  for (int s = 0; s < 256; s++){
    int t = dir ? (255 - s) : s;
    // prefetch gx for the nonlinearity threads (issued early, hidden under dot)
    float gxv0=0, gxv1=0, gxv2=0, gxv3=0;
    if (tid < 64){
      int b = tid>>4, j2 = tid&15;
      const float* gp = gx + (size_t)((b<<8) + t)*2048 + dir*1024 + j0 + j2;
      gxv0 = gp[0]; gxv1 = gp[256]; gxv2 = gp[512]; gxv3 = gp[768];
    }
    // gate dot: acc[b] = sum_k W_hh[grow][k] * h[b][k] over k in [16kc,16kc+16)
    float a0=0.f,a1=0.f,a2=0.f,a3=0.f;
    {
      int base = (kc<<7) + ((kc&7)<<2);   // hswz(kc*16)
      #pragma unroll
      for (int kk=0; kk<16; kk++){
        float4 hv = *(const float4*)&h_swz[base + (kk<<3)];
        a0 = fmaf(wreg[kk], hv.x, a0);
        a1 = fmaf(wreg[kk], hv.y, a1);
        a2 = fmaf(wreg[kk], hv.z, a2);
        a3 = fmaf(wreg[kk], hv.w, a3);
      }
    }
    #pragma unroll
    for (int m=1; m<16; m<<=1){
      a0 += __shfl_xor(a0, m, 64);
      a1 += __shfl_xor(a1, m, 64);
      a2 += __shfl_xor(a2, m, 64);
      a3 += __shfl_xor(a3, m, 64);
    }
    if (kc == 0){
      gate_lds[0][r]=a0; gate_lds[1][r]=a1; gate_lds[2][r]=a2; gate_lds[3][r]=a3;
    }
    __syncthreads();
    if (tid < 64){            // wave 0: nonlinearity + publish + poll
      int b = tid>>4, j2 = tid&15;
      float gi = gxv0 + gate_lds[b][ 0+j2];
      float gf = gxv1 + gate_lds[b][16+j2];
      float gg = gxv2 + gate_lds[b][32+j2];
      float go = gxv3 + gate_lds[b][48+j2];
      c_reg  = sigf(gf)*c_reg + sigf(gi)*tanhf_fast(gg);
      float h = sigf(go)*tanhf_fast(c_reg);
      __hip_atomic_store(&hb[((s&1)<<10) + (b<<8) + j0 + j2], h,
                         __ATOMIC_RELAXED, __HIP_MEMORY_SCOPE_AGENT);
      if (tid == 0)
        __hip_atomic_store(&myflags[w<<5], (unsigned)(s+1),
                           __ATOMIC_RELEASE, __HIP_MEMORY_SCOPE_AGENT);
      hcat[(size_t)((b<<8) + t)*512 + (dir<<8) + j0 + j2] = h;   // after release: not in its vmcnt window
      // parallel poll: lane i watches slot i's flag
      unsigned target = (unsigned)(s+1);
      unsigned* fp = myflags + ((tid&15)<<5);
      for(;;){
        unsigned v = (tid < 16)
          ? __hip_atomic_load(fp, __ATOMIC_ACQUIRE, __HIP_MEMORY_SCOPE_AGENT)
          : target;
        if (__all((int)(v >= target))) break;
      }
    }
    __syncthreads();
    // refill h for next step from the buffer just completed (par = s&1)
    {
      int k = tid & 255, bb = tid >> 8;
      float hv = __hip_atomic_load(&hb[((s&1)<<10) + (bb<<8) + k],
                                   __ATOMIC_RELAXED, __HIP_MEMORY_SCOPE_AGENT);
      h_swz[hswz(k) + bb] = hv;
    }
    __syncthreads();
  }
}

// ---------------- fused additive attention + softmax + ctx + classifier ----------------
__global__ __launch_bounds__(256) void k_attn(
    const float* __restrict__ q, const float* __restrict__ kmat,
    const float* __restrict__ h, const float* __restrict__ v,
    const float* __restrict__ clsW, const float* __restrict__ clsb,
    float* __restrict__ out){
  int bt = blockIdx.x;           // b*256 + t
  int b  = bt >> 8;
  int tid = threadIdx.x;
  __shared__ float q_s[512], v_s[512], p_s[256], red[8], ctx_s[512], part[240];
  *(float2*)&q_s[tid<<1] = *(const float2*)&q[(size_t)bt*512 + (tid<<1)];
  *(float2*)&v_s[tid<<1] = *(const float2*)&v[tid<<1];
  __syncthreads();
  const float* kp = kmat + (size_t)((b<<8) + tid)*512;
  float sc = 0.f;
  for (int d=0; d<512; d+=4){
    float4 kv = *(const float4*)&kp[d];
    sc += v_s[d+0]*tanhf_fast(q_s[d+0]+kv.x)
        + v_s[d+1]*tanhf_fast(q_s[d+1]+kv.y)
        + v_s[d+2]*tanhf_fast(q_s[d+2]+kv.z)
        + v_s[d+3]*tanhf_fast(q_s[d+3]+kv.w);
  }
  int wv = tid>>6, lane = tid&63;
  float m = sc;
  #pragma unroll
  for (int o=1;o<64;o<<=1) m = fmaxf(m, __shfl_xor(m,o,64));
  if (lane==0) red[wv] = m;
  __syncthreads();
  m = fmaxf(fmaxf(red[0],red[1]), fmaxf(red[2],red[3]));
  float p = __expf(sc - m);
  p_s[tid] = p;
  float sum = p;
  #pragma unroll
  for (int o=1;o<64;o<<=1) sum += __shfl_xor(sum,o,64);
  if (lane==0) red[4+wv] = sum;
  __syncthreads();
  float inv = 1.0f/(red[4]+red[5]+red[6]+red[7]);
  float cx=0.f, cy=0.f;
  for (int s2=0; s2<256; s2++){
    float pw = p_s[s2];
    float2 hv = *(const float2*)&h[(size_t)((b<<8)+s2)*512 + (tid<<1)];
    cx = fmaf(pw, hv.x, cx); cy = fmaf(pw, hv.y, cy);
  }
  ctx_s[tid<<1] = cx*inv; ctx_s[(tid<<1)+1] = cy*inv;
  __syncthreads();
  if (tid < 240){
    int c = tid>>4, ch = tid&15;
    const float* wrow = clsW + (size_t)c*512 + (ch<<5);
    const float* cc = &ctx_s[ch<<5];
    float acc = 0.f;
    #pragma unroll
    for (int i=0;i<32;i++) acc = fmaf(wrow[i], cc[i], acc);
    part[tid] = acc;
  }
  __syncthreads();
  if (tid < 15){
    float o = clsb[tid];
    #pragma unroll
    for (int i=0;i<16;i++) o += part[(tid<<4)+i];
    out[(size_t)bt*15 + tid] = o;
  }
}

extern "C" void kernel_launch(void* const* d_in, const int* in_sizes, int n_in,
                              void* d_out, int out_size, void* d_ws, size_t ws_size,
                              hipStream_t stream){
  (void)in_sizes; (void)n_in; (void)out_size; (void)ws_size;
  const int*   ids    = (const int*)  d_in[0];
  const float* emb    = (const float*)d_in[1];
  const float* w_ih0  = (const float*)d_in[2];
  const float* w_hh0  = (const float*)d_in[3];
  const float* b0     = (const float*)d_in[4];
  const float* w_ih   = (const float*)d_in[5];
  const float* w_hh   = (const float*)d_in[6];
  const float* b      = (const float*)d_in[7];
  const float* attn_W = (const float*)d_in[8];
  const float* attn_U = (const float*)d_in[9];
  const float* attn_v = (const float*)d_in[10];
  const float* cls_W  = (const float*)d_in[11];
  const float* cls_b  = (const float*)d_in[12];
  float* out = (float*)d_out;

  float* ws   = (float*)d_ws;
  float* x    = ws;                  // 131072
  float* gx   = x  + 131072;         // 2097152 (1024 x 2048)
  float* hA   = gx + 2097152;        // 524288  (1024 x 512)
  float* hB   = hA + 524288;         // 524288
  float* hbuf = hB + 524288;         // 3 layers x 4096
  unsigned* flg = (unsigned*)(hbuf + 3*4096);  // 3 layers x 1024 uints
  float* qb   = gx;                  // reuse gx after recurrences done
  float* kb   = gx + 524288;

  hipMemsetAsync(flg, 0, 3*1024*sizeof(unsigned), stream);
  k_embed<<<512, 256, 0, stream>>>(ids, emb, x);

  dim3 gBig(16, 32);   // M=1024, N=2048
  dim3 gQK(16, 8);     // M=1024, N=512

  // layer 0
  k_gemm_bias<<<gBig, 256, 0, stream>>>(x, w_ih0, b0, gx, 2048, 128);
  k_lstm<<<32, 1024, 0, stream>>>(gx, w_hh0, hA, hbuf + 0*4096, flg + 0*1024);
  // layer 1
  k_gemm_bias<<<gBig, 256, 0, stream>>>(hA, w_ih, b, gx, 2048, 512);
  k_lstm<<<32, 1024, 0, stream>>>(gx, w_hh, hB, hbuf + 1*4096, flg + 1*1024);
  // layer 2
  k_gemm_bias<<<gBig, 256, 0, stream>>>(hB, w_ih + 2048*512, b + 2048, gx, 2048, 512);
  k_lstm<<<32, 1024, 0, stream>>>(gx, w_hh + 2048*256, hA, hbuf + 2*4096, flg + 2*1024);
  // attention projections
  k_gemm_bias<<<gQK, 256, 0, stream>>>(hA, attn_W, nullptr, qb, 512, 512);
  k_gemm_bias<<<gQK, 256, 0, stream>>>(hA, attn_U, nullptr, kb, 512, 512);
  // fused scores/softmax/ctx/classifier
  k_attn<<<1024, 256, 0, stream>>>(qb, kb, hA, attn_v, cls_W, cls_b, out);
}